// Round 4
// baseline (1716.135 us; speedup 1.0000x reference)
//
#include <hip/hip_runtime.h>
#include <hip/hip_bf16.h>

#define N_USERS_C 100000
#define N_ITEMS_C 20000
#define N_NODES_C 120000
#define E_TOT_C   400000
#define D_IN_C    192
#define HID_C     256
#define NEG_C     0.2f
#define CLAMP_C   1000.0f

typedef __attribute__((ext_vector_type(8))) short bfrag;
typedef __attribute__((ext_vector_type(4))) float ffrag;

__device__ __forceinline__ float bf2f(unsigned short u){
  return __uint_as_float(((unsigned)u) << 16);
}
__device__ __forceinline__ float ldf(const void* p, long i, int isf32){
  return isf32 ? ((const float*)p)[i] : bf2f(((const unsigned short*)p)[i]);
}
__device__ __forceinline__ float sane(float v){
  return (v > -1e30f && v < 1e30f) ? v : 0.f;
}

// ---------- dtype discriminator (inputs) ----------
// bf16 N(0,0.05): exponent field always < 129. f32 read as shorts: mantissa
// low-halves ~random -> ~50% have (u>>7)&0xFF >= 129.
__global__ __launch_bounds__(256) void detect_dtype(const unsigned short* __restrict__ ue,
                                                    int* __restrict__ flag){
  __shared__ int cnt[256];
  int tid = threadIdx.x; int c = 0;
  for (int i = tid; i < 8192; i += 256){
    unsigned e = (ue[i] >> 7) & 0xFFu;
    if (e >= 129u) c++;
  }
  cnt[tid] = c; __syncthreads();
  if (tid == 0){
    int s = 0;
    for (int i = 0; i < 256; i++) s += cnt[i];
    *flag = (s > 100) ? 1 : 0;
  }
}

// ---------- convert small weight tensors into a bf16 arena ----------
#define NCONV 18
struct ConvArgs { const void* src[NCONV]; int n[NCONV]; int off[NCONV]; };

__global__ __launch_bounds__(256) void conv_small(ConvArgs a, __hip_bfloat16* __restrict__ arena,
                                                  const int* __restrict__ flag){
  int t = blockIdx.x;
  int f32 = *flag;
  const void* s = a.src[t];
  int n = a.n[t], off = a.off[t];
  for (int i = threadIdx.x; i < n; i += 256)
    arena[off + i] = __float2bfloat16(ldf(s, i, f32));
}

// Bt (272 x K): rows 0..255 = W^T; 256..256+H-1 = fold(Ws,a_s); next H = fold(Wd,a_d); rest 0.
__global__ void prep_bt(const __hip_bfloat16* __restrict__ Ws,
                        const __hip_bfloat16* __restrict__ Wd,
                        const __hip_bfloat16* __restrict__ as_,
                        const __hip_bfloat16* __restrict__ ad_,
                        __hip_bfloat16* __restrict__ Bt, int K, int H, int C){
  int idx = blockIdx.x * 256 + threadIdx.x;
  if (idx >= 272 * K) return;
  int col = idx / K, k = idx - col * K;
  float v;
  if (col < 256) {
    v = __bfloat162float(Ws[k * 256 + col]);
  } else if (col < 256 + H) {
    int h = col - 256; float s = 0.f;
    for (int c = 0; c < C; c++)
      s += __bfloat162float(Ws[k * 256 + h * C + c]) * __bfloat162float(as_[h * C + c]);
    v = s;
  } else if (col < 256 + 2 * H) {
    int h = col - 256 - H; float s = 0.f;
    for (int c = 0; c < C; c++)
      s += __bfloat162float(Wd[k * 256 + h * C + c]) * __bfloat162float(ad_[h * C + c]);
    v = s;
  } else v = 0.f;
  Bt[(long)col * K + k] = __float2bfloat16(v);
}

// x: (120000 x 192) bf16. Users: emb | zeros. Movies: item_emb cols 0..63.
__global__ void assemble_x(const void* __restrict__ ue, const void* __restrict__ ie,
                           __hip_bfloat16* __restrict__ x, const int* __restrict__ flag){
  long idx = (long)blockIdx.x * 256 + threadIdx.x;
  if (idx >= (long)N_NODES_C * D_IN_C) return;
  int f32 = *flag;
  int n = (int)(idx / D_IN_C); int c = (int)(idx - (long)n * D_IN_C);
  if (n < N_USERS_C) {
    x[idx] = __float2bfloat16((c < 64) ? ldf(ue, (long)n * 64 + c, f32) : 0.f);
  } else if (c < 64) {
    x[idx] = __float2bfloat16(ldf(ie, (long)(n - N_USERS_C) * 64 + c, f32));
  }
}

// One wave per movie: genre MLP (20->64->64), tag MLP (1128->64->64); x cols 64..191.
__global__ __launch_bounds__(64) void movie_mlp(const void* __restrict__ mov_x,
    const __hip_bfloat16* __restrict__ gW1, const __hip_bfloat16* __restrict__ gb1,
    const __hip_bfloat16* __restrict__ gW2, const __hip_bfloat16* __restrict__ gb2,
    const __hip_bfloat16* __restrict__ tW1, const __hip_bfloat16* __restrict__ tb1,
    const __hip_bfloat16* __restrict__ tW2, const __hip_bfloat16* __restrict__ tb2,
    __hip_bfloat16* __restrict__ x, const int* __restrict__ flag){
  int m = blockIdx.x; int h = threadIdx.x;
  int f32 = *flag;
  __shared__ float hid[64];
  long rbase = (long)m * 1148;
  float s = 0.f;
  for (int k = 0; k < 20; k++)
    s += ldf(mov_x, rbase + k, f32) * __bfloat162float(gW1[k * 64 + h]);
  s += __bfloat162float(gb1[h]); s = fmaxf(s, 0.f);
  hid[h] = s; __syncthreads();
  float o = 0.f;
  for (int k = 0; k < 64; k++) o += hid[k] * __bfloat162float(gW2[k * 64 + h]);
  o += __bfloat162float(gb2[h]);
  x[(long)(N_USERS_C + m) * D_IN_C + 64 + h] = __float2bfloat16(o);
  __syncthreads();
  s = 0.f;
  for (int k = 0; k < 1128; k++)
    s += ldf(mov_x, rbase + 20 + k, f32) * __bfloat162float(tW1[k * 64 + h]);
  s += __bfloat162float(tb1[h]); s = fmaxf(s, 0.f);
  hid[h] = s; __syncthreads();
  o = 0.f;
  for (int k = 0; k < 64; k++) o += hid[k] * __bfloat162float(tW2[k * 64 + h]);
  o += __bfloat162float(tb2[h]);
  x[(long)(N_USERS_C + m) * D_IN_C + 128 + h] = __float2bfloat16(o);
}

// MFMA GEMM: A (M x K bf16) @ Bt^T -> Hout (M x 256 bf16) + als/ald (f32, M x natt).
__global__ __launch_bounds__(256) void gemm_fused(
    const __hip_bfloat16* __restrict__ A, const __hip_bfloat16* __restrict__ Bt,
    __hip_bfloat16* __restrict__ Hout, float* __restrict__ als, float* __restrict__ ald,
    int K, int natt){
  int wave = threadIdx.x >> 6;
  int lane = threadIdx.x & 63;
  int l15 = lane & 15;
  int quad = lane >> 4;
  int rowbase = blockIdx.x * 64 + wave * 16;
  ffrag acc[17];
#pragma unroll
  for (int i = 0; i < 17; i++) acc[i] = (ffrag){0.f, 0.f, 0.f, 0.f};
  const short* As = (const short*)A;
  const short* Bs = (const short*)Bt;
  long arow = (long)(rowbase + l15) * K;
  for (int k0 = 0; k0 < K; k0 += 32) {
    int koff = k0 + quad * 8;
    bfrag af = *(const bfrag*)(As + arow + koff);
#pragma unroll
    for (int nt = 0; nt < 17; nt++) {
      bfrag bf = *(const bfrag*)(Bs + (long)(nt * 16 + l15) * K + koff);
      acc[nt] = __builtin_amdgcn_mfma_f32_16x16x32_bf16(af, bf, acc[nt], 0, 0, 0);
    }
  }
  int col = l15;
#pragma unroll
  for (int reg = 0; reg < 4; reg++) {
    int grow = rowbase + quad * 4 + reg;
    long obase = (long)grow * 256;
#pragma unroll
    for (int nt = 0; nt < 16; nt++)
      Hout[obase + nt * 16 + col] = __float2bfloat16(acc[nt][reg]);
    float v = acc[16][reg];
    if (col < natt) als[grow * natt + col] = v;
    else if (col < 2 * natt) ald[grow * natt + (col - natt)] = v;
  }
}

// ---------- CSR build (in-edges per dst) ----------
__global__ void zero_deg(int* __restrict__ deg){
  int i = blockIdx.x * 256 + threadIdx.x;
  if (i < N_NODES_C) deg[i] = 0;
}

__global__ void deg_count(const int* __restrict__ ei, int* __restrict__ deg){
  int e = blockIdx.x * 256 + threadIdx.x;
  if (e >= E_TOT_C) return;
  int dst = ei[E_TOT_C + e];
  if (dst >= 0 && dst < N_NODES_C) atomicAdd(&deg[dst], 1);
}

__global__ __launch_bounds__(256) void scan_deg(const int* __restrict__ deg,
                                                int* __restrict__ ptrn){
  __shared__ int part[256];
  const int CH = 469;  // 256*469 = 120064 >= 120000
  int tid = threadIdx.x;
  int base = tid * CH;
  int s = 0;
  for (int i = 0; i < CH; i++) { int idx = base + i; if (idx < N_NODES_C) s += deg[idx]; }
  part[tid] = s; __syncthreads();
  if (tid == 0) {
    int run = 0;
    for (int i = 0; i < 256; i++) { int t = part[i]; part[i] = run; run += t; }
    ptrn[N_NODES_C] = run;
  }
  __syncthreads();
  int run = part[tid];
  for (int i = 0; i < CH; i++) {
    int idx = base + i;
    if (idx < N_NODES_C) { ptrn[idx] = run; run += deg[idx]; }
  }
}

// cursor == deg (re-zeroed). Stores SRC node id directly.
__global__ void scatter_edges(const int* __restrict__ ei, const int* __restrict__ ptrn,
                              int* __restrict__ cursor, int* __restrict__ elist_src){
  int e = blockIdx.x * 256 + threadIdx.x;
  if (e >= E_TOT_C) return;
  int dst = ei[E_TOT_C + e];
  if (dst < 0 || dst >= N_NODES_C) return;
  int pos = atomicAdd(&cursor[dst], 1);
  elist_src[ptrn[dst] + pos] = ei[e];
}

// ---------- layer 1: per-node softmax aggregation (8 heads) + bias + elu ----------
// Writes h1 as bf16 (internal tensor feeding the layer-2 GEMM).
__global__ __launch_bounds__(256) void aggregate1(
    const int* __restrict__ ptrn, const int* __restrict__ elist_src,
    const float* __restrict__ als, const float* __restrict__ ald,
    const __hip_bfloat16* __restrict__ hs, const __hip_bfloat16* __restrict__ bias,
    __hip_bfloat16* __restrict__ h1){
  int node = blockIdx.x * 4 + (threadIdx.x >> 6);
  if (node >= N_NODES_C) return;
  int lane = threadIdx.x & 63;
  int c0 = lane * 4;
  int h = lane >> 3;
  int beg = ptrn[node], end = ptrn[node + 1];
  float aldv = sane(ald[node * 8 + h]);
  float mx = -1e30f;
  for (int i = beg; i < end; i++) {
    int src = elist_src[i]; src = src < 0 ? 0 : (src >= N_NODES_C ? N_NODES_C - 1 : src);
    float ev = sane(als[src * 8 + h]) + aldv;
    ev = ev > 0.f ? ev : NEG_C * ev;
    mx = fmaxf(mx, ev);
  }
  float wsum = 0.f, a0 = 0.f, a1 = 0.f, a2 = 0.f, a3 = 0.f;
  for (int i = beg; i < end; i++) {
    int src = elist_src[i]; src = src < 0 ? 0 : (src >= N_NODES_C ? N_NODES_C - 1 : src);
    float ev = sane(als[src * 8 + h]) + aldv;
    ev = ev > 0.f ? ev : NEG_C * ev;
    float w = __expf(ev - mx);
    wsum += w;
    ushort4 hv = *(const ushort4*)((const unsigned short*)hs + (long)src * 256 + c0);
    a0 += w * bf2f(hv.x); a1 += w * bf2f(hv.y);
    a2 += w * bf2f(hv.z); a3 += w * bf2f(hv.w);
  }
  float inv = 1.f / (wsum + 1e-16f);
  float v0 = a0 * inv + __bfloat162float(bias[c0 + 0]);
  float v1 = a1 * inv + __bfloat162float(bias[c0 + 1]);
  float v2 = a2 * inv + __bfloat162float(bias[c0 + 2]);
  float v3 = a3 * inv + __bfloat162float(bias[c0 + 3]);
  v0 = v0 > 0.f ? v0 : (__expf(v0) - 1.f);
  v1 = v1 > 0.f ? v1 : (__expf(v1) - 1.f);
  v2 = v2 > 0.f ? v2 : (__expf(v2) - 1.f);
  v3 = v3 > 0.f ? v3 : (__expf(v3) - 1.f);
  v0 = fminf(fmaxf(v0, -CLAMP_C), CLAMP_C);
  v1 = fminf(fmaxf(v1, -CLAMP_C), CLAMP_C);
  v2 = fminf(fmaxf(v2, -CLAMP_C), CLAMP_C);
  v3 = fminf(fmaxf(v3, -CLAMP_C), CLAMP_C);
  long ob = (long)node * 256 + c0;
  h1[ob + 0] = __float2bfloat16(v0); h1[ob + 1] = __float2bfloat16(v1);
  h1[ob + 2] = __float2bfloat16(v2); h1[ob + 3] = __float2bfloat16(v3);
}

// ---------- layer 2: 1 head, no activation. OUTPUT IS FLOAT32. ----------
__global__ __launch_bounds__(256) void aggregate2(
    const int* __restrict__ ptrn, const int* __restrict__ elist_src,
    const float* __restrict__ als, const float* __restrict__ ald,
    const __hip_bfloat16* __restrict__ hs, const __hip_bfloat16* __restrict__ bias,
    float* __restrict__ out){
  int node = blockIdx.x * 4 + (threadIdx.x >> 6);
  if (node >= N_NODES_C) return;
  int lane = threadIdx.x & 63;
  int c0 = lane * 4;
  int beg = ptrn[node], end = ptrn[node + 1];
  float aldv = sane(ald[node]);
  float mx = -1e30f;
  for (int i = beg; i < end; i++) {
    int src = elist_src[i]; src = src < 0 ? 0 : (src >= N_NODES_C ? N_NODES_C - 1 : src);
    float ev = sane(als[src]) + aldv;
    ev = ev > 0.f ? ev : NEG_C * ev;
    mx = fmaxf(mx, ev);
  }
  float wsum = 0.f, a0 = 0.f, a1 = 0.f, a2 = 0.f, a3 = 0.f;
  for (int i = beg; i < end; i++) {
    int src = elist_src[i]; src = src < 0 ? 0 : (src >= N_NODES_C ? N_NODES_C - 1 : src);
    float ev = sane(als[src]) + aldv;
    ev = ev > 0.f ? ev : NEG_C * ev;
    float w = __expf(ev - mx);
    wsum += w;
    ushort4 hv = *(const ushort4*)((const unsigned short*)hs + (long)src * 256 + c0);
    a0 += w * bf2f(hv.x); a1 += w * bf2f(hv.y);
    a2 += w * bf2f(hv.z); a3 += w * bf2f(hv.w);
  }
  float inv = 1.f / (wsum + 1e-16f);
  float4 v;
  v.x = a0 * inv + __bfloat162float(bias[c0 + 0]);
  v.y = a1 * inv + __bfloat162float(bias[c0 + 1]);
  v.z = a2 * inv + __bfloat162float(bias[c0 + 2]);
  v.w = a3 * inv + __bfloat162float(bias[c0 + 3]);
  v.x = fminf(fmaxf(v.x, -CLAMP_C), CLAMP_C);
  v.y = fminf(fmaxf(v.y, -CLAMP_C), CLAMP_C);
  v.z = fminf(fmaxf(v.z, -CLAMP_C), CLAMP_C);
  v.w = fminf(fmaxf(v.w, -CLAMP_C), CLAMP_C);
  *(float4*)(out + (long)node * 256 + c0) = v;
}

// ptr tail as f32, base derived from runtime out_size.
__global__ void write_tail(float* __restrict__ out, int out_size){
  if (threadIdx.x == 0 && blockIdx.x == 0) {
    out[out_size - 3] = 0.f;
    out[out_size - 2] = (float)N_USERS_C;
    out[out_size - 1] = (float)N_NODES_C;
  }
}

extern "C" void kernel_launch(void* const* d_in, const int* in_sizes, int n_in,
                              void* d_out, int out_size, void* d_ws, size_t ws_size,
                              hipStream_t stream) {
  const void* mov_x    = d_in[2];
  const int*  ei       = (const int*)d_in[3];
  const void* user_emb = d_in[4];
  const void* item_emb = d_in[5];

  char* ws = (char*)d_ws;
  size_t off = 0;
  auto alloc = [&](size_t bytes) -> void* {
    void* p = ws + off; off += (bytes + 255) / 256 * 256; return p;
  };
  int* flag   = (int*)alloc(4);
  __hip_bfloat16* arena = (__hip_bfloat16*)alloc(312832 * 2);
  __hip_bfloat16* Bt1 = (__hip_bfloat16*)alloc(272 * 192 * 2);
  __hip_bfloat16* Bt2 = (__hip_bfloat16*)alloc(272 * 256 * 2);
  int* ptrn   = (int*)alloc((N_NODES_C + 1) * 4);
  int* deg    = (int*)alloc(N_NODES_C * 4);          // reused as scatter cursor
  int* elist  = (int*)alloc(E_TOT_C * 4);            // stores src node ids
  float* als  = (float*)alloc((size_t)N_NODES_C * 8 * 4);
  float* ald  = (float*)alloc((size_t)N_NODES_C * 8 * 4);
  __hip_bfloat16* x  = (__hip_bfloat16*)alloc((size_t)N_NODES_C * D_IN_C * 2); // 46.08 MB
  __hip_bfloat16* hs = (__hip_bfloat16*)alloc((size_t)N_NODES_C * HID_C * 2);  // 61.44 MB
  // h1 (bf16, 61.44 MB) parks in d_out's f32 buffer (122.88 MB): written by
  // aggregate1, read by gemm2, then d_out fully overwritten (f32) by aggregate2.
  __hip_bfloat16* h1 = (__hip_bfloat16*)d_out;

  // arena layout (element offsets)
  const int oWs1=0, oWd1=49152, oas1=98304, oad1=98560, ob1=98816,
            oWs2=99072, oWd2=164608, oas2=230144, oad2=230400, ob2=230656,
            ogW1=230912, ogb1=232192, ogW2=232256, ogb2=236352,
            otW1=236416, otb1=308608, otW2=308672, otb2=312768;

  detect_dtype<<<1, 256, 0, stream>>>((const unsigned short*)user_emb, flag);

  ConvArgs ca;
  const int srcidx[NCONV] = {14,15,16,17,18,19,20,21,22,23,6,7,8,9,10,11,12,13};
  const int offs[NCONV]   = {oWs1,oWd1,oas1,oad1,ob1,oWs2,oWd2,oas2,oad2,ob2,
                             ogW1,ogb1,ogW2,ogb2,otW1,otb1,otW2,otb2};
  const int ns[NCONV]     = {49152,49152,256,256,256,65536,65536,256,256,256,
                             1280,64,4096,64,72192,64,4096,64};
  for (int i = 0; i < NCONV; i++) { ca.src[i] = d_in[srcidx[i]]; ca.n[i] = ns[i]; ca.off[i] = offs[i]; }
  conv_small<<<NCONV, 256, 0, stream>>>(ca, arena, flag);

  assemble_x<<<(int)(((long)N_NODES_C * D_IN_C + 255) / 256), 256, 0, stream>>>(
      user_emb, item_emb, x, flag);
  movie_mlp<<<N_ITEMS_C, 64, 0, stream>>>(mov_x,
      arena + ogW1, arena + ogb1, arena + ogW2, arena + ogb2,
      arena + otW1, arena + otb1, arena + otW2, arena + otb2, x, flag);

  prep_bt<<<(272 * 192 + 255) / 256, 256, 0, stream>>>(
      arena + oWs1, arena + oWd1, arena + oas1, arena + oad1, Bt1, 192, 8, 32);
  prep_bt<<<(272 * 256 + 255) / 256, 256, 0, stream>>>(
      arena + oWs2, arena + oWd2, arena + oas2, arena + oad2, Bt2, 256, 1, 256);

  // CSR of in-edges (deg -> ptrn -> scatter; deg re-zeroed as cursor)
  zero_deg<<<(N_NODES_C + 255) / 256, 256, 0, stream>>>(deg);
  deg_count<<<(E_TOT_C + 255) / 256, 256, 0, stream>>>(ei, deg);
  scan_deg<<<1, 256, 0, stream>>>(deg, ptrn);
  zero_deg<<<(N_NODES_C + 255) / 256, 256, 0, stream>>>(deg);
  scatter_edges<<<(E_TOT_C + 255) / 256, 256, 0, stream>>>(ei, ptrn, deg, elist);

  // layer 1
  gemm_fused<<<N_NODES_C / 64, 256, 0, stream>>>(x, Bt1, hs, als, ald, 192, 8);
  aggregate1<<<N_NODES_C / 4, 256, 0, stream>>>(ptrn, elist, als, ald, hs, arena + ob1, h1);

  // layer 2
  gemm_fused<<<N_NODES_C / 64, 256, 0, stream>>>(h1, Bt2, hs, als, ald, 256, 1);
  aggregate2<<<N_NODES_C / 4, 256, 0, stream>>>(ptrn, elist, als, ald, hs, arena + ob2,
                                                (float*)d_out);
  write_tail<<<1, 64, 0, stream>>>((float*)d_out, out_size);
}

// Round 5
// 1191.260 us; speedup vs baseline: 1.4406x; 1.4406x over previous
//
#include <hip/hip_runtime.h>
#include <hip/hip_bf16.h>

#define N_USERS_C 100000
#define N_ITEMS_C 20000
#define N_NODES_C 120000
#define E_TOT_C   400000
#define D_IN_C    192
#define HID_C     256
#define NEG_C     0.2f
#define CLAMP_C   1000.0f
#define KPAD_C    1152   // 1148 padded to multiple of 32

typedef __attribute__((ext_vector_type(8))) short bfrag;
typedef __attribute__((ext_vector_type(4))) float ffrag;

__device__ __forceinline__ float bf2f(unsigned short u){
  return __uint_as_float(((unsigned)u) << 16);
}
__device__ __forceinline__ float ldf(const void* p, long i, int isf32){
  return isf32 ? ((const float*)p)[i] : bf2f(((const unsigned short*)p)[i]);
}
__device__ __forceinline__ float sane(float v){
  return (v > -1e30f && v < 1e30f) ? v : 0.f;
}

// ---------- dtype discriminator (inputs) ----------
__global__ __launch_bounds__(256) void detect_dtype(const unsigned short* __restrict__ ue,
                                                    int* __restrict__ flag){
  __shared__ int cnt[256];
  int tid = threadIdx.x; int c = 0;
  for (int i = tid; i < 8192; i += 256){
    unsigned e = (ue[i] >> 7) & 0xFFu;
    if (e >= 129u) c++;
  }
  cnt[tid] = c; __syncthreads();
  if (tid == 0){
    int s = 0;
    for (int i = 0; i < 256; i++) s += cnt[i];
    *flag = (s > 100) ? 1 : 0;
  }
}

// ---------- convert small weight tensors into a bf16 arena ----------
#define NCONV 18
struct ConvArgs { const void* src[NCONV]; int n[NCONV]; int off[NCONV]; };

// grid = NCONV * 8 blocks; block handles tensor (b>>3), slice (b&7).
__global__ __launch_bounds__(256) void conv_small(ConvArgs a, __hip_bfloat16* __restrict__ arena,
                                                  const int* __restrict__ flag){
  int t = blockIdx.x >> 3, sub = blockIdx.x & 7;
  int f32 = *flag;
  const void* s = a.src[t];
  int n = a.n[t], off = a.off[t];
  for (int i = sub * 256 + threadIdx.x; i < n; i += 2048)
    arena[off + i] = __float2bfloat16(ldf(s, i, f32));
}

// Bt (272 x K): rows 0..255 = W^T; 256..256+H-1 = fold(Ws,a_s); next H = fold(Wd,a_d); rest 0.
__global__ void prep_bt(const __hip_bfloat16* __restrict__ Ws,
                        const __hip_bfloat16* __restrict__ Wd,
                        const __hip_bfloat16* __restrict__ as_,
                        const __hip_bfloat16* __restrict__ ad_,
                        __hip_bfloat16* __restrict__ Bt, int K, int H, int C){
  int idx = blockIdx.x * 256 + threadIdx.x;
  if (idx >= 272 * K) return;
  int col = idx / K, k = idx - col * K;
  float v;
  if (col < 256) {
    v = __bfloat162float(Ws[k * 256 + col]);
  } else if (col < 256 + H) {
    int h = col - 256; float s = 0.f;
    for (int c = 0; c < C; c++)
      s += __bfloat162float(Ws[k * 256 + h * C + c]) * __bfloat162float(as_[h * C + c]);
    v = s;
  } else if (col < 256 + 2 * H) {
    int h = col - 256 - H; float s = 0.f;
    for (int c = 0; c < C; c++)
      s += __bfloat162float(Wd[k * 256 + h * C + c]) * __bfloat162float(ad_[h * C + c]);
    v = s;
  } else v = 0.f;
  Bt[(long)col * K + k] = __float2bfloat16(v);
}

// x: (120000 x 192) bf16. Users: emb | zeros. Movies: item_emb cols 0..63.
__global__ void assemble_x(const void* __restrict__ ue, const void* __restrict__ ie,
                           __hip_bfloat16* __restrict__ x, const int* __restrict__ flag){
  long idx = (long)blockIdx.x * 256 + threadIdx.x;
  if (idx >= (long)N_NODES_C * D_IN_C) return;
  int f32 = *flag;
  int n = (int)(idx / D_IN_C); int c = (int)(idx - (long)n * D_IN_C);
  if (n < N_USERS_C) {
    x[idx] = __float2bfloat16((c < 64) ? ldf(ue, (long)n * 64 + c, f32) : 0.f);
  } else if (c < 64) {
    x[idx] = __float2bfloat16(ldf(ie, (long)(n - N_USERS_C) * 64 + c, f32));
  }
}

// ---------- movie feature path: MFMA instead of scalar MLP ----------
// mov_x (20000 x 1148) -> bf16 padded (20000 x 1152)
__global__ void conv_movx(const void* __restrict__ mv, __hip_bfloat16* __restrict__ out,
                          const int* __restrict__ flag){
  long idx = (long)blockIdx.x * 256 + threadIdx.x;
  if (idx >= (long)N_ITEMS_C * KPAD_C) return;
  int f32 = *flag;
  int m = (int)(idx / KPAD_C); int c = (int)(idx - (long)m * KPAD_C);
  float v = (c < 1148) ? ldf(mv, (long)m * 1148 + c, f32) : 0.f;
  out[idx] = __float2bfloat16(v);
}

// W1t (128 x 1152): row n<64 -> gW1 col n (k<20); row n>=64 -> tW1 col n-64 (20<=k<1148).
__global__ void prep_w1t(const __hip_bfloat16* __restrict__ gW1,
                         const __hip_bfloat16* __restrict__ tW1,
                         __hip_bfloat16* __restrict__ W1t){
  int idx = blockIdx.x * 256 + threadIdx.x;
  if (idx >= 128 * KPAD_C) return;
  int n = idx / KPAD_C, k = idx - n * KPAD_C;
  __hip_bfloat16 v = __float2bfloat16(0.f);
  if (n < 64) { if (k < 20) v = gW1[k * 64 + n]; }
  else       { if (k >= 20 && k < 1148) v = tW1[(k - 20) * 64 + (n - 64)]; }
  W1t[idx] = v;
}

// W2t (128 x 128) blockdiag of gW2 / tW2.
__global__ void prep_w2t(const __hip_bfloat16* __restrict__ gW2,
                         const __hip_bfloat16* __restrict__ tW2,
                         __hip_bfloat16* __restrict__ W2t){
  int idx = blockIdx.x * 256 + threadIdx.x;
  if (idx >= 128 * 128) return;
  int n = idx >> 7, k = idx & 127;
  __hip_bfloat16 v = __float2bfloat16(0.f);
  if (n < 64) { if (k < 64)  v = gW2[k * 64 + n]; }
  else        { if (k >= 64) v = tW2[(k - 64) * 64 + (n - 64)]; }
  W2t[idx] = v;
}

__global__ void prep_movie_bias(const __hip_bfloat16* __restrict__ gb1,
                                const __hip_bfloat16* __restrict__ tb1,
                                const __hip_bfloat16* __restrict__ gb2,
                                const __hip_bfloat16* __restrict__ tb2,
                                __hip_bfloat16* __restrict__ b1c,
                                __hip_bfloat16* __restrict__ b2c){
  int i = threadIdx.x;
  if (i < 64)       b1c[i] = gb1[i];
  else if (i < 128) b1c[i] = tb1[i - 64];
  else if (i < 192) b2c[i - 128] = gb2[i - 128];
  else              b2c[i - 128] = tb2[i - 192];
}

// MFMA GEMM, N=128 (8 n-tiles), M rows with guard, optional relu, bias add.
__global__ __launch_bounds__(256) void movie_gemm(
    const __hip_bfloat16* __restrict__ A, int lda, int M,
    const __hip_bfloat16* __restrict__ Bt, int K,
    const __hip_bfloat16* __restrict__ bias, int do_relu,
    __hip_bfloat16* __restrict__ out, int ldo, int ocol){
  int wave = threadIdx.x >> 6;
  int lane = threadIdx.x & 63;
  int l15 = lane & 15;
  int quad = lane >> 4;
  int rowbase = blockIdx.x * 64 + wave * 16;
  int ar = rowbase + l15; if (ar >= M) ar = M - 1;
  ffrag acc[8];
#pragma unroll
  for (int i = 0; i < 8; i++) acc[i] = (ffrag){0.f, 0.f, 0.f, 0.f};
  const short* As = (const short*)A;
  const short* Bs = (const short*)Bt;
  long arow = (long)ar * lda;
  for (int k0 = 0; k0 < K; k0 += 32) {
    int koff = k0 + quad * 8;
    bfrag af = *(const bfrag*)(As + arow + koff);
#pragma unroll
    for (int nt = 0; nt < 8; nt++) {
      bfrag bf = *(const bfrag*)(Bs + (long)(nt * 16 + l15) * K + koff);
      acc[nt] = __builtin_amdgcn_mfma_f32_16x16x32_bf16(af, bf, acc[nt], 0, 0, 0);
    }
  }
#pragma unroll
  for (int reg = 0; reg < 4; reg++) {
    int grow = rowbase + quad * 4 + reg;
    if (grow >= M) continue;
#pragma unroll
    for (int nt = 0; nt < 8; nt++) {
      float v = acc[nt][reg] + __bfloat162float(bias[nt * 16 + l15]);
      if (do_relu) v = fmaxf(v, 0.f);
      out[(long)grow * ldo + ocol + nt * 16 + l15] = __float2bfloat16(v);
    }
  }
}

// MFMA GEMM: A (M x K bf16) @ Bt^T -> Hout (M x 256 bf16) + als/ald (f32, M x natt).
__global__ __launch_bounds__(256) void gemm_fused(
    const __hip_bfloat16* __restrict__ A, const __hip_bfloat16* __restrict__ Bt,
    __hip_bfloat16* __restrict__ Hout, float* __restrict__ als, float* __restrict__ ald,
    int K, int natt){
  int wave = threadIdx.x >> 6;
  int lane = threadIdx.x & 63;
  int l15 = lane & 15;
  int quad = lane >> 4;
  int rowbase = blockIdx.x * 64 + wave * 16;
  ffrag acc[17];
#pragma unroll
  for (int i = 0; i < 17; i++) acc[i] = (ffrag){0.f, 0.f, 0.f, 0.f};
  const short* As = (const short*)A;
  const short* Bs = (const short*)Bt;
  long arow = (long)(rowbase + l15) * K;
  for (int k0 = 0; k0 < K; k0 += 32) {
    int koff = k0 + quad * 8;
    bfrag af = *(const bfrag*)(As + arow + koff);
#pragma unroll
    for (int nt = 0; nt < 17; nt++) {
      bfrag bf = *(const bfrag*)(Bs + (long)(nt * 16 + l15) * K + koff);
      acc[nt] = __builtin_amdgcn_mfma_f32_16x16x32_bf16(af, bf, acc[nt], 0, 0, 0);
    }
  }
  int col = l15;
#pragma unroll
  for (int reg = 0; reg < 4; reg++) {
    int grow = rowbase + quad * 4 + reg;
    long obase = (long)grow * 256;
#pragma unroll
    for (int nt = 0; nt < 16; nt++)
      Hout[obase + nt * 16 + col] = __float2bfloat16(acc[nt][reg]);
    float v = acc[16][reg];
    if (col < natt) als[grow * natt + col] = v;
    else if (col < 2 * natt) ald[grow * natt + (col - natt)] = v;
  }
}

// ---------- CSR build (in-edges per dst) ----------
__global__ void zero_deg(int* __restrict__ deg){
  int i = blockIdx.x * 256 + threadIdx.x;
  if (i < N_NODES_C) deg[i] = 0;
}

__global__ void deg_count(const int* __restrict__ ei, int* __restrict__ deg){
  int e = blockIdx.x * 256 + threadIdx.x;
  if (e >= E_TOT_C) return;
  int dst = ei[E_TOT_C + e];
  if (dst >= 0 && dst < N_NODES_C) atomicAdd(&deg[dst], 1);
}

__global__ __launch_bounds__(256) void scan_deg(const int* __restrict__ deg,
                                                int* __restrict__ ptrn){
  __shared__ int part[256];
  const int CH = 469;
  int tid = threadIdx.x;
  int base = tid * CH;
  int s = 0;
  for (int i = 0; i < CH; i++) { int idx = base + i; if (idx < N_NODES_C) s += deg[idx]; }
  part[tid] = s; __syncthreads();
  if (tid == 0) {
    int run = 0;
    for (int i = 0; i < 256; i++) { int t = part[i]; part[i] = run; run += t; }
    ptrn[N_NODES_C] = run;
  }
  __syncthreads();
  int run = part[tid];
  for (int i = 0; i < CH; i++) {
    int idx = base + i;
    if (idx < N_NODES_C) { ptrn[idx] = run; run += deg[idx]; }
  }
}

__global__ void scatter_edges(const int* __restrict__ ei, const int* __restrict__ ptrn,
                              int* __restrict__ cursor, int* __restrict__ elist_src){
  int e = blockIdx.x * 256 + threadIdx.x;
  if (e >= E_TOT_C) return;
  int dst = ei[E_TOT_C + e];
  if (dst < 0 || dst >= N_NODES_C) return;
  int pos = atomicAdd(&cursor[dst], 1);
  elist_src[ptrn[dst] + pos] = ei[e];
}

// ---------- layer 1: per-node softmax aggregation (8 heads) + bias + elu ----------
__global__ __launch_bounds__(256) void aggregate1(
    const int* __restrict__ ptrn, const int* __restrict__ elist_src,
    const float* __restrict__ als, const float* __restrict__ ald,
    const __hip_bfloat16* __restrict__ hs, const __hip_bfloat16* __restrict__ bias,
    __hip_bfloat16* __restrict__ h1){
  int node = blockIdx.x * 4 + (threadIdx.x >> 6);
  if (node >= N_NODES_C) return;
  int lane = threadIdx.x & 63;
  int c0 = lane * 4;
  int h = lane >> 3;
  int beg = ptrn[node], end = ptrn[node + 1];
  float aldv = sane(ald[node * 8 + h]);
  float mx = -1e30f;
  for (int i = beg; i < end; i++) {
    int src = elist_src[i]; src = src < 0 ? 0 : (src >= N_NODES_C ? N_NODES_C - 1 : src);
    float ev = sane(als[src * 8 + h]) + aldv;
    ev = ev > 0.f ? ev : NEG_C * ev;
    mx = fmaxf(mx, ev);
  }
  float wsum = 0.f, a0 = 0.f, a1 = 0.f, a2 = 0.f, a3 = 0.f;
  for (int i = beg; i < end; i++) {
    int src = elist_src[i]; src = src < 0 ? 0 : (src >= N_NODES_C ? N_NODES_C - 1 : src);
    float ev = sane(als[src * 8 + h]) + aldv;
    ev = ev > 0.f ? ev : NEG_C * ev;
    float w = __expf(ev - mx);
    wsum += w;
    ushort4 hv = *(const ushort4*)((const unsigned short*)hs + (long)src * 256 + c0);
    a0 += w * bf2f(hv.x); a1 += w * bf2f(hv.y);
    a2 += w * bf2f(hv.z); a3 += w * bf2f(hv.w);
  }
  float inv = 1.f / (wsum + 1e-16f);
  float v0 = a0 * inv + __bfloat162float(bias[c0 + 0]);
  float v1 = a1 * inv + __bfloat162float(bias[c0 + 1]);
  float v2 = a2 * inv + __bfloat162float(bias[c0 + 2]);
  float v3 = a3 * inv + __bfloat162float(bias[c0 + 3]);
  v0 = v0 > 0.f ? v0 : (__expf(v0) - 1.f);
  v1 = v1 > 0.f ? v1 : (__expf(v1) - 1.f);
  v2 = v2 > 0.f ? v2 : (__expf(v2) - 1.f);
  v3 = v3 > 0.f ? v3 : (__expf(v3) - 1.f);
  v0 = fminf(fmaxf(v0, -CLAMP_C), CLAMP_C);
  v1 = fminf(fmaxf(v1, -CLAMP_C), CLAMP_C);
  v2 = fminf(fmaxf(v2, -CLAMP_C), CLAMP_C);
  v3 = fminf(fmaxf(v3, -CLAMP_C), CLAMP_C);
  long ob = (long)node * 256 + c0;
  h1[ob + 0] = __float2bfloat16(v0); h1[ob + 1] = __float2bfloat16(v1);
  h1[ob + 2] = __float2bfloat16(v2); h1[ob + 3] = __float2bfloat16(v3);
}

// ---------- layer 2: 1 head, no activation. OUTPUT IS FLOAT32. ----------
__global__ __launch_bounds__(256) void aggregate2(
    const int* __restrict__ ptrn, const int* __restrict__ elist_src,
    const float* __restrict__ als, const float* __restrict__ ald,
    const __hip_bfloat16* __restrict__ hs, const __hip_bfloat16* __restrict__ bias,
    float* __restrict__ out){
  int node = blockIdx.x * 4 + (threadIdx.x >> 6);
  if (node >= N_NODES_C) return;
  int lane = threadIdx.x & 63;
  int c0 = lane * 4;
  int beg = ptrn[node], end = ptrn[node + 1];
  float aldv = sane(ald[node]);
  float mx = -1e30f;
  for (int i = beg; i < end; i++) {
    int src = elist_src[i]; src = src < 0 ? 0 : (src >= N_NODES_C ? N_NODES_C - 1 : src);
    float ev = sane(als[src]) + aldv;
    ev = ev > 0.f ? ev : NEG_C * ev;
    mx = fmaxf(mx, ev);
  }
  float wsum = 0.f, a0 = 0.f, a1 = 0.f, a2 = 0.f, a3 = 0.f;
  for (int i = beg; i < end; i++) {
    int src = elist_src[i]; src = src < 0 ? 0 : (src >= N_NODES_C ? N_NODES_C - 1 : src);
    float ev = sane(als[src]) + aldv;
    ev = ev > 0.f ? ev : NEG_C * ev;
    float w = __expf(ev - mx);
    wsum += w;
    ushort4 hv = *(const ushort4*)((const unsigned short*)hs + (long)src * 256 + c0);
    a0 += w * bf2f(hv.x); a1 += w * bf2f(hv.y);
    a2 += w * bf2f(hv.z); a3 += w * bf2f(hv.w);
  }
  float inv = 1.f / (wsum + 1e-16f);
  float4 v;
  v.x = a0 * inv + __bfloat162float(bias[c0 + 0]);
  v.y = a1 * inv + __bfloat162float(bias[c0 + 1]);
  v.z = a2 * inv + __bfloat162float(bias[c0 + 2]);
  v.w = a3 * inv + __bfloat162float(bias[c0 + 3]);
  v.x = fminf(fmaxf(v.x, -CLAMP_C), CLAMP_C);
  v.y = fminf(fmaxf(v.y, -CLAMP_C), CLAMP_C);
  v.z = fminf(fmaxf(v.z, -CLAMP_C), CLAMP_C);
  v.w = fminf(fmaxf(v.w, -CLAMP_C), CLAMP_C);
  *(float4*)(out + (long)node * 256 + c0) = v;
}

__global__ void write_tail(float* __restrict__ out, int out_size){
  if (threadIdx.x == 0 && blockIdx.x == 0) {
    out[out_size - 3] = 0.f;
    out[out_size - 2] = (float)N_USERS_C;
    out[out_size - 1] = (float)N_NODES_C;
  }
}

extern "C" void kernel_launch(void* const* d_in, const int* in_sizes, int n_in,
                              void* d_out, int out_size, void* d_ws, size_t ws_size,
                              hipStream_t stream) {
  const void* mov_x    = d_in[2];
  const int*  ei       = (const int*)d_in[3];
  const void* user_emb = d_in[4];
  const void* item_emb = d_in[5];

  char* ws = (char*)d_ws;
  size_t off = 0;
  auto alloc = [&](size_t bytes) -> void* {
    void* p = ws + off; off += (bytes + 255) / 256 * 256; return p;
  };
  int* flag   = (int*)alloc(4);
  __hip_bfloat16* arena = (__hip_bfloat16*)alloc(312832 * 2);
  __hip_bfloat16* Bt1 = (__hip_bfloat16*)alloc(272 * 192 * 2);
  __hip_bfloat16* Bt2 = (__hip_bfloat16*)alloc(272 * 256 * 2);
  __hip_bfloat16* W1t = (__hip_bfloat16*)alloc(128 * KPAD_C * 2);
  __hip_bfloat16* W2t = (__hip_bfloat16*)alloc(128 * 128 * 2);
  __hip_bfloat16* b1c = (__hip_bfloat16*)alloc(128 * 2);
  __hip_bfloat16* b2c = (__hip_bfloat16*)alloc(128 * 2);
  int* ptrn   = (int*)alloc((N_NODES_C + 1) * 4);
  int* deg    = (int*)alloc(N_NODES_C * 4);
  int* elist  = (int*)alloc(E_TOT_C * 4);
  float* als  = (float*)alloc((size_t)N_NODES_C * 8 * 4);
  float* ald  = (float*)alloc((size_t)N_NODES_C * 8 * 4);
  __hip_bfloat16* x  = (__hip_bfloat16*)alloc((size_t)N_NODES_C * D_IN_C * 2); // 46.08 MB
  __hip_bfloat16* hs = (__hip_bfloat16*)alloc((size_t)N_NODES_C * HID_C * 2);  // 61.44 MB
  // d_out (f32, 122.88 MB) hosts two dead-before-aggregate2 temporaries:
  //   h1 (bf16 61.44 MB) at byte 0; mov_bf (bf16 46.08 MB) at byte 61,440,000.
  __hip_bfloat16* h1     = (__hip_bfloat16*)d_out;
  __hip_bfloat16* mov_bf = (__hip_bfloat16*)((char*)d_out + 61440000);
  __hip_bfloat16* hid    = hs;  // movie hidden (20000x128) parks in hs

  const int oWs1=0, oWd1=49152, oas1=98304, oad1=98560, ob1=98816,
            oWs2=99072, oWd2=164608, oas2=230144, oad2=230400, ob2=230656,
            ogW1=230912, ogb1=232192, ogW2=232256, ogb2=236352,
            otW1=236416, otb1=308608, otW2=308672, otb2=312768;

  detect_dtype<<<1, 256, 0, stream>>>((const unsigned short*)user_emb, flag);

  ConvArgs ca;
  const int srcidx[NCONV] = {14,15,16,17,18,19,20,21,22,23,6,7,8,9,10,11,12,13};
  const int offs[NCONV]   = {oWs1,oWd1,oas1,oad1,ob1,oWs2,oWd2,oas2,oad2,ob2,
                             ogW1,ogb1,ogW2,ogb2,otW1,otb1,otW2,otb2};
  const int ns[NCONV]     = {49152,49152,256,256,256,65536,65536,256,256,256,
                             1280,64,4096,64,72192,64,4096,64};
  for (int i = 0; i < NCONV; i++) { ca.src[i] = d_in[srcidx[i]]; ca.n[i] = ns[i]; ca.off[i] = offs[i]; }
  conv_small<<<NCONV * 8, 256, 0, stream>>>(ca, arena, flag);

  // movie feature path (MFMA)
  conv_movx<<<(int)(((long)N_ITEMS_C * KPAD_C + 255) / 256), 256, 0, stream>>>(
      mov_x, mov_bf, flag);
  prep_w1t<<<(128 * KPAD_C + 255) / 256, 256, 0, stream>>>(arena + ogW1, arena + otW1, W1t);
  prep_w2t<<<(128 * 128 + 255) / 256, 256, 0, stream>>>(arena + ogW2, arena + otW2, W2t);
  prep_movie_bias<<<1, 256, 0, stream>>>(arena + ogb1, arena + otb1,
                                         arena + ogb2, arena + otb2, b1c, b2c);
  assemble_x<<<(int)(((long)N_NODES_C * D_IN_C + 255) / 256), 256, 0, stream>>>(
      user_emb, item_emb, x, flag);
  movie_gemm<<<(N_ITEMS_C + 63) / 64, 256, 0, stream>>>(
      mov_bf, KPAD_C, N_ITEMS_C, W1t, KPAD_C, b1c, 1, hid, 128, 0);
  movie_gemm<<<(N_ITEMS_C + 63) / 64, 256, 0, stream>>>(
      hid, 128, N_ITEMS_C, W2t, 128, b2c, 0,
      x + (long)N_USERS_C * D_IN_C, D_IN_C, 64);

  prep_bt<<<(272 * 192 + 255) / 256, 256, 0, stream>>>(
      arena + oWs1, arena + oWd1, arena + oas1, arena + oad1, Bt1, 192, 8, 32);
  prep_bt<<<(272 * 256 + 255) / 256, 256, 0, stream>>>(
      arena + oWs2, arena + oWd2, arena + oas2, arena + oad2, Bt2, 256, 1, 256);

  // CSR of in-edges
  zero_deg<<<(N_NODES_C + 255) / 256, 256, 0, stream>>>(deg);
  deg_count<<<(E_TOT_C + 255) / 256, 256, 0, stream>>>(ei, deg);
  scan_deg<<<1, 256, 0, stream>>>(deg, ptrn);
  zero_deg<<<(N_NODES_C + 255) / 256, 256, 0, stream>>>(deg);
  scatter_edges<<<(E_TOT_C + 255) / 256, 256, 0, stream>>>(ei, ptrn, deg, elist);

  // layer 1
  gemm_fused<<<N_NODES_C / 64, 256, 0, stream>>>(x, Bt1, hs, als, ald, 192, 8);
  aggregate1<<<N_NODES_C / 4, 256, 0, stream>>>(ptrn, elist, als, ald, hs, arena + ob1, h1);

  // layer 2
  gemm_fused<<<N_NODES_C / 64, 256, 0, stream>>>(h1, Bt2, hs, als, ald, 256, 1);
  aggregate2<<<N_NODES_C / 4, 256, 0, stream>>>(ptrn, elist, als, ald, hs, arena + ob2,
                                                (float*)d_out);
  write_tail<<<1, 64, 0, stream>>>((float*)d_out, out_size);
}